// Round 1
// baseline (349.619 us; speedup 1.0000x reference)
//
#include <hip/hip_runtime.h>
#include <hip/hip_bf16.h>

#define B_DIM 8192
#define I_DIM 1024
#define H_DIM 1024

#define BM 128
#define BK 64
#define NTHREADS 256

typedef __attribute__((ext_vector_type(8))) short short8;
typedef __attribute__((ext_vector_type(4))) float f32x4;

static __device__ __forceinline__ short f2b(float f) {
    __bf16 h = (__bf16)f;
    return __builtin_bit_cast(short, h);
}

static __device__ __forceinline__ short8 pack8(float4 a, float4 b) {
    short8 s;
    s[0] = f2b(a.x); s[1] = f2b(a.y); s[2] = f2b(a.z); s[3] = f2b(a.w);
    s[4] = f2b(b.x); s[5] = f2b(b.y); s[6] = f2b(b.z); s[7] = f2b(b.w);
    return s;
}

// swizzled LDS short-index for element (row, k) of a [128][64] bf16 tile
static __device__ __forceinline__ int swz(int row, int k) {
    int byte = (row << 7) + (k << 1);
    byte ^= (row & 7) << 4;
    return byte >> 1;
}

static __device__ __forceinline__ float sigmoid_f(float x) {
    return 1.0f / (1.0f + __expf(-x));
}

static __device__ __forceinline__ float tanh_fast(float x) {
    x = fminf(fmaxf(x, -15.0f), 15.0f);
    float e = __expf(2.0f * x);
    return (e - 1.0f) / (e + 1.0f);
}

__global__ __launch_bounds__(NTHREADS, 2) void lstm_fused_kernel(
    const float* __restrict__ x, const float* __restrict__ hprev,
    const float* __restrict__ cprev, const float* __restrict__ Wx,
    const float* __restrict__ Wh, const float* __restrict__ bh,
    float* __restrict__ out)
{
    __shared__ __align__(16) short As[BM * BK];  // [row][k] swizzled, bf16 bits
    __shared__ __align__(16) short Bs[BM * BK];  // [n][k]   swizzled, bf16 bits

    // XCD-aware swizzle: 2048 blocks, 8 XCDs -> contiguous 256-chunks per XCD
    int bid = blockIdx.x;
    bid = (bid & 7) * 256 + (bid >> 3);
    const int mt = bid >> 5;   // 0..63  batch tile
    const int ht = bid & 31;   // 0..31  h tile
    const int m0 = mt * BM;
    const int h0 = ht * 32;

    const int t    = threadIdx.x;
    const int lane = t & 63;
    const int w    = t >> 6;     // wave 0..3
    const int wr   = w >> 1;     // row half
    const int wc   = w & 1;      // col half (h half)

    // staging: thread covers (srow + p*32, k-chunk of 8 floats)
    const int srow   = t >> 3;   // 0..31
    const int sk     = (t & 7) * 8;

    f32x4 acc[4][4] = {};        // [m-frag][gate]

    #pragma unroll 1
    for (int phase = 0; phase < 2; ++phase) {
        const float* __restrict__ Ap = phase ? hprev : x;
        const float* __restrict__ Bp = phase ? Wh : Wx;
        #pragma unroll 1
        for (int kk = 0; kk < 1024; kk += BK) {
            __syncthreads();
            // ---- stage A tile: rows = batch rows, fp32 -> bf16 ----
            #pragma unroll
            for (int p = 0; p < 4; ++p) {
                const int row = srow + p * 32;
                const float4* src = (const float4*)(Ap + (size_t)(m0 + row) * I_DIM + kk + sk);
                float4 v0 = src[0];
                float4 v1 = src[1];
                *(short8*)&As[swz(row, sk)] = pack8(v0, v1);
            }
            // ---- stage B tile: n -> (gate, h) mapping ----
            // n in [0,128): gate=(n>>4)&3, h = h0 + (n>>6)*16 + (n&15)
            #pragma unroll
            for (int p = 0; p < 4; ++p) {
                const int n    = srow + p * 32;
                const int gate = (n >> 4) & 3;
                const int hcol = h0 + ((n >> 6) << 4) + (n & 15);
                const float4* src = (const float4*)(Bp + (size_t)((gate << 10) + hcol) * 1024 + kk + sk);
                float4 v0 = src[0];
                float4 v1 = src[1];
                *(short8*)&Bs[swz(n, sk)] = pack8(v0, v1);
            }
            __syncthreads();
            // ---- compute: 2 k-slices of 32, 4x4 fragments ----
            #pragma unroll
            for (int ks = 0; ks < 2; ++ks) {
                const int kb = ks * 32 + ((lane >> 4) << 3);
                short8 a[4], b[4];
                #pragma unroll
                for (int m = 0; m < 4; ++m)
                    a[m] = *(const short8*)&As[swz(wr * 64 + m * 16 + (lane & 15), kb)];
                #pragma unroll
                for (int j = 0; j < 4; ++j)
                    b[j] = *(const short8*)&Bs[swz(wc * 64 + j * 16 + (lane & 15), kb)];
                #pragma unroll
                for (int m = 0; m < 4; ++m)
                    #pragma unroll
                    for (int j = 0; j < 4; ++j)
                        acc[m][j] = __builtin_amdgcn_mfma_f32_16x16x32_bf16(a[m], b[j], acc[m][j], 0, 0, 0);
            }
        }
    }

    // ---- fused LSTM epilogue, fully in-register ----
    // D layout: col = lane&15, row = (lane>>4)*4 + reg
    const int cl = lane & 15;
    const int rg = lane >> 4;
    const int h  = h0 + wc * 16 + cl;
    const float b_i = bh[0 * H_DIM + h];
    const float b_f = bh[1 * H_DIM + h];
    const float b_g = bh[2 * H_DIM + h];
    const float b_o = bh[3 * H_DIM + h];

    #pragma unroll
    for (int m = 0; m < 4; ++m) {
        #pragma unroll
        for (int r = 0; r < 4; ++r) {
            const int row = m0 + wr * 64 + m * 16 + rg * 4 + r;
            const float pi = acc[m][0][r] + b_i;
            const float pf = acc[m][1][r] + b_f;
            const float pg = acc[m][2][r] + b_g;
            const float po = acc[m][3][r] + b_o;
            const float iv = sigmoid_f(pi);
            const float fv = sigmoid_f(pf);
            const float gv = tanh_fast(pg);
            const float ov = sigmoid_f(po);
            const float cp = cprev[(size_t)row * H_DIM + h];
            const float cn = fv * cp + iv * gv;
            const float hn = ov * tanh_fast(cn);
            out[(size_t)row * H_DIM + h] = hn;
            out[(size_t)B_DIM * H_DIM + (size_t)row * H_DIM + h] = cn;
        }
    }
}

extern "C" void kernel_launch(void* const* d_in, const int* in_sizes, int n_in,
                              void* d_out, int out_size, void* d_ws, size_t ws_size,
                              hipStream_t stream) {
    const float* x     = (const float*)d_in[0];
    const float* hprev = (const float*)d_in[1];
    const float* cprev = (const float*)d_in[2];
    const float* Wx    = (const float*)d_in[3];
    const float* Wh    = (const float*)d_in[4];
    const float* bh    = (const float*)d_in[5];
    float* out = (float*)d_out;

    dim3 grid(2048);
    dim3 block(NTHREADS);
    hipLaunchKernelGGL(lstm_fused_kernel, grid, block, 0, stream,
                       x, hprev, cprev, Wx, Wh, bh, out);
}

// Round 2
// 191.547 us; speedup vs baseline: 1.8252x; 1.8252x over previous
//
#include <hip/hip_runtime.h>
#include <hip/hip_bf16.h>
#include <stdint.h>

#define B_DIM 8192
#define I_DIM 1024
#define H_DIM 1024

#define BM 128
#define BK 64
#define NTHREADS 256

typedef __attribute__((ext_vector_type(8))) short short8;
typedef __attribute__((ext_vector_type(4))) float f32x4;

static __device__ __forceinline__ short f2b(float f) {
    __bf16 h = (__bf16)f;
    return __builtin_bit_cast(short, h);
}

static __device__ __forceinline__ short8 pack8(float4 a, float4 b) {
    short8 s;
    s[0] = f2b(a.x); s[1] = f2b(a.y); s[2] = f2b(a.z); s[3] = f2b(a.w);
    s[4] = f2b(b.x); s[5] = f2b(b.y); s[6] = f2b(b.z); s[7] = f2b(b.w);
    return s;
}

static __device__ __forceinline__ float sigmoid_f(float x) {
    return 1.0f / (1.0f + __expf(-x));
}

static __device__ __forceinline__ float tanh_fast(float x) {
    x = fminf(fmaxf(x, -15.0f), 15.0f);
    float e = __expf(2.0f * x);
    return (e - 1.0f) / (e + 1.0f);
}

static __device__ __forceinline__ void load_lds16(const void* gptr, void* lptr) {
    __builtin_amdgcn_global_load_lds(
        (const __attribute__((address_space(1))) uint32_t*)gptr,
        (__attribute__((address_space(3))) uint32_t*)lptr, 16, 0, 0);
}

// ---------------------------------------------------------------------------
// Pass 1: fp32 -> bf16 conversion into workspace.
//   A_ws [8192][2048]: k<1024 from x, k>=1024 from hprev
//   B_ws [4096][2048]: row n = gate*1024+h; k<1024 from Wx, k>=1024 from Wh
// ---------------------------------------------------------------------------
__global__ __launch_bounds__(256) void convert_kernel(
    const float* __restrict__ x, const float* __restrict__ h,
    const float* __restrict__ wx, const float* __restrict__ wh,
    short* __restrict__ Aw, short* __restrict__ Bw)
{
    const int64_t nx = (int64_t)B_DIM * I_DIM / 8;   // 1048576 groups of 8
    const int64_t nw = (int64_t)4 * H_DIM * I_DIM / 8; // 524288
    const int64_t total = 2 * nx + 2 * nw;
    for (int64_t g = (int64_t)blockIdx.x * blockDim.x + threadIdx.x; g < total;
         g += (int64_t)gridDim.x * blockDim.x) {
        const float* src;
        short* dst;
        if (g < nx) {
            int64_t r = g >> 7, kc = (g & 127) * 8;
            src = x + g * 8; dst = Aw + r * 2048 + kc;
        } else if (g < 2 * nx) {
            int64_t gg = g - nx;
            int64_t r = gg >> 7, kc = (gg & 127) * 8;
            src = h + gg * 8; dst = Aw + r * 2048 + 1024 + kc;
        } else if (g < 2 * nx + nw) {
            int64_t gg = g - 2 * nx;
            int64_t r = gg >> 7, kc = (gg & 127) * 8;
            src = wx + gg * 8; dst = Bw + r * 2048 + kc;
        } else {
            int64_t gg = g - 2 * nx - nw;
            int64_t r = gg >> 7, kc = (gg & 127) * 8;
            src = wh + gg * 8; dst = Bw + r * 2048 + 1024 + kc;
        }
        float4 v0 = ((const float4*)src)[0];
        float4 v1 = ((const float4*)src)[1];
        *(short8*)dst = pack8(v0, v1);
    }
}

// ---------------------------------------------------------------------------
// Pass 2: m97-structure GEMM (128x128 tile, BK=64, global_load_lds width=16)
// with fused in-register LSTM epilogue.
// M=8192 (batch), N-tile = 4 gates x 32 h, K=2048 (I then H).
// ---------------------------------------------------------------------------
__global__ __launch_bounds__(NTHREADS, 3) void lstm_gemm_kernel(
    const short* __restrict__ Aw, const short* __restrict__ Bw,
    const float* __restrict__ cprev, const float* __restrict__ bh,
    float* __restrict__ out)
{
    __shared__ __align__(16) short As[BM * BK];  // [row][k] linear
    __shared__ __align__(16) short Bs[BM * BK];  // [n][k]   linear

    // XCD-aware swizzle: 2048 blocks, 8 XCDs -> contiguous 256-chunks per XCD
    int bid = blockIdx.x;
    bid = (bid & 7) * 256 + (bid >> 3);
    const int mt = bid >> 5;   // 0..63  batch tile
    const int ht = bid & 31;   // 0..31  h tile
    const int m0 = mt * BM;
    const int h0 = ht * 32;

    const int t    = threadIdx.x;
    const int lane = t & 63;
    const int w    = t >> 6;     // wave 0..3
    const int wr   = w >> 1;     // row half
    const int wc   = w & 1;      // col half (h half)

    // per-lane source addressing for global_load_lds:
    // each 1KB issue covers 8 rows; lane l -> row +l/8, k elems (l%8)*8
    const int lr = lane >> 3;
    const int lk = (lane & 7) * 8;

    int64_t a_off[4], b_off[4];
    #pragma unroll
    for (int i = 0; i < 4; ++i) {
        const int r = w * 32 + i * 8 + lr;
        a_off[i] = (int64_t)(m0 + r) * 2048 + lk;
        const int gate = (r >> 4) & 3;
        const int hcol = h0 + ((r >> 6) << 4) + (r & 15);
        b_off[i] = (int64_t)(gate * 1024 + hcol) * 2048 + lk;
    }

    f32x4 acc[4][4] = {};        // [m-frag][gate]

    #pragma unroll 1
    for (int kk = 0; kk < 2048; kk += BK) {
        __syncthreads();
        #pragma unroll
        for (int i = 0; i < 4; ++i)
            load_lds16(Aw + a_off[i] + kk, &As[(w * 32 + i * 8) * BK]);
        #pragma unroll
        for (int i = 0; i < 4; ++i)
            load_lds16(Bw + b_off[i] + kk, &Bs[(w * 32 + i * 8) * BK]);
        __syncthreads();
        #pragma unroll
        for (int ks = 0; ks < 2; ++ks) {
            const int kb = ks * 32 + ((lane >> 4) << 3);
            short8 a[4], b[4];
            #pragma unroll
            for (int m = 0; m < 4; ++m)
                a[m] = *(const short8*)&As[(wr * 64 + m * 16 + (lane & 15)) * BK + kb];
            #pragma unroll
            for (int j = 0; j < 4; ++j)
                b[j] = *(const short8*)&Bs[(wc * 64 + j * 16 + (lane & 15)) * BK + kb];
            #pragma unroll
            for (int m = 0; m < 4; ++m)
                #pragma unroll
                for (int j = 0; j < 4; ++j)
                    acc[m][j] = __builtin_amdgcn_mfma_f32_16x16x32_bf16(a[m], b[j], acc[m][j], 0, 0, 0);
        }
    }

    // ---- fused LSTM epilogue, fully in-register ----
    // D layout: col = lane&15, row = (lane>>4)*4 + reg
    const int cl = lane & 15;
    const int rg = lane >> 4;
    const int h  = h0 + wc * 16 + cl;
    const float b_i = bh[0 * H_DIM + h];
    const float b_f = bh[1 * H_DIM + h];
    const float b_g = bh[2 * H_DIM + h];
    const float b_o = bh[3 * H_DIM + h];

    #pragma unroll
    for (int m = 0; m < 4; ++m) {
        #pragma unroll
        for (int r = 0; r < 4; ++r) {
            const int row = m0 + wr * 64 + m * 16 + rg * 4 + r;
            const float pi = acc[m][0][r] + b_i;
            const float pf = acc[m][1][r] + b_f;
            const float pg = acc[m][2][r] + b_g;
            const float po = acc[m][3][r] + b_o;
            const float iv = sigmoid_f(pi);
            const float fv = sigmoid_f(pf);
            const float gv = tanh_fast(pg);
            const float ov = sigmoid_f(po);
            const float cp = cprev[(size_t)row * H_DIM + h];
            const float cn = fv * cp + iv * gv;
            const float hn = ov * tanh_fast(cn);
            out[(size_t)row * H_DIM + h] = hn;
            out[(size_t)B_DIM * H_DIM + (size_t)row * H_DIM + h] = cn;
        }
    }
}

// ---------------------------------------------------------------------------
// Fallback (round-0 kernel) if workspace is too small for bf16 operands.
// ---------------------------------------------------------------------------
static __device__ __forceinline__ int swz(int row, int k) {
    int byte = (row << 7) + (k << 1);
    byte ^= (row & 7) << 4;
    return byte >> 1;
}

__global__ __launch_bounds__(NTHREADS, 2) void lstm_fallback_kernel(
    const float* __restrict__ x, const float* __restrict__ hprev,
    const float* __restrict__ cprev, const float* __restrict__ Wx,
    const float* __restrict__ Wh, const float* __restrict__ bh,
    float* __restrict__ out)
{
    __shared__ __align__(16) short As[BM * BK];
    __shared__ __align__(16) short Bs[BM * BK];

    int bid = blockIdx.x;
    bid = (bid & 7) * 256 + (bid >> 3);
    const int mt = bid >> 5;
    const int ht = bid & 31;
    const int m0 = mt * BM;
    const int h0 = ht * 32;

    const int t    = threadIdx.x;
    const int lane = t & 63;
    const int w    = t >> 6;
    const int wr   = w >> 1;
    const int wc   = w & 1;

    const int srow   = t >> 3;
    const int sk     = (t & 7) * 8;

    f32x4 acc[4][4] = {};

    #pragma unroll 1
    for (int phase = 0; phase < 2; ++phase) {
        const float* __restrict__ Ap = phase ? hprev : x;
        const float* __restrict__ Bp = phase ? Wh : Wx;
        #pragma unroll 1
        for (int kk = 0; kk < 1024; kk += BK) {
            __syncthreads();
            #pragma unroll
            for (int p = 0; p < 4; ++p) {
                const int row = srow + p * 32;
                const float4* src = (const float4*)(Ap + (size_t)(m0 + row) * I_DIM + kk + sk);
                float4 v0 = src[0];
                float4 v1 = src[1];
                *(short8*)&As[swz(row, sk)] = pack8(v0, v1);
            }
            #pragma unroll
            for (int p = 0; p < 4; ++p) {
                const int n    = srow + p * 32;
                const int gate = (n >> 4) & 3;
                const int hcol = h0 + ((n >> 6) << 4) + (n & 15);
                const float4* src = (const float4*)(Bp + (size_t)((gate << 10) + hcol) * 1024 + kk + sk);
                float4 v0 = src[0];
                float4 v1 = src[1];
                *(short8*)&Bs[swz(n, sk)] = pack8(v0, v1);
            }
            __syncthreads();
            #pragma unroll
            for (int ks = 0; ks < 2; ++ks) {
                const int kb = ks * 32 + ((lane >> 4) << 3);
                short8 a[4], b[4];
                #pragma unroll
                for (int m = 0; m < 4; ++m)
                    a[m] = *(const short8*)&As[swz(wr * 64 + m * 16 + (lane & 15), kb)];
                #pragma unroll
                for (int j = 0; j < 4; ++j)
                    b[j] = *(const short8*)&Bs[swz(wc * 64 + j * 16 + (lane & 15), kb)];
                #pragma unroll
                for (int m = 0; m < 4; ++m)
                    #pragma unroll
                    for (int j = 0; j < 4; ++j)
                        acc[m][j] = __builtin_amdgcn_mfma_f32_16x16x32_bf16(a[m], b[j], acc[m][j], 0, 0, 0);
            }
        }
    }

    const int cl = lane & 15;
    const int rg = lane >> 4;
    const int h  = h0 + wc * 16 + cl;
    const float b_i = bh[0 * H_DIM + h];
    const float b_f = bh[1 * H_DIM + h];
    const float b_g = bh[2 * H_DIM + h];
    const float b_o = bh[3 * H_DIM + h];

    #pragma unroll
    for (int m = 0; m < 4; ++m) {
        #pragma unroll
        for (int r = 0; r < 4; ++r) {
            const int row = m0 + wr * 64 + m * 16 + rg * 4 + r;
            const float pi = acc[m][0][r] + b_i;
            const float pf = acc[m][1][r] + b_f;
            const float pg = acc[m][2][r] + b_g;
            const float po = acc[m][3][r] + b_o;
            const float iv = sigmoid_f(pi);
            const float fv = sigmoid_f(pf);
            const float gv = tanh_fast(pg);
            const float ov = sigmoid_f(po);
            const float cp = cprev[(size_t)row * H_DIM + h];
            const float cn = fv * cp + iv * gv;
            const float hn = ov * tanh_fast(cn);
            out[(size_t)row * H_DIM + h] = hn;
            out[(size_t)B_DIM * H_DIM + (size_t)row * H_DIM + h] = cn;
        }
    }
}

extern "C" void kernel_launch(void* const* d_in, const int* in_sizes, int n_in,
                              void* d_out, int out_size, void* d_ws, size_t ws_size,
                              hipStream_t stream) {
    const float* x     = (const float*)d_in[0];
    const float* hprev = (const float*)d_in[1];
    const float* cprev = (const float*)d_in[2];
    const float* Wx    = (const float*)d_in[3];
    const float* Wh    = (const float*)d_in[4];
    const float* bh    = (const float*)d_in[5];
    float* out = (float*)d_out;

    const size_t need = ((size_t)B_DIM * 2048 + (size_t)4096 * 2048) * sizeof(short);
    if (ws_size >= need && d_ws != nullptr) {
        short* Aw = (short*)d_ws;
        short* Bw = Aw + (size_t)B_DIM * 2048;
        hipLaunchKernelGGL(convert_kernel, dim3(2048), dim3(256), 0, stream,
                           x, hprev, Wx, Wh, Aw, Bw);
        hipLaunchKernelGGL(lstm_gemm_kernel, dim3(2048), dim3(NTHREADS), 0, stream,
                           Aw, Bw, cprev, bh, out);
    } else {
        hipLaunchKernelGGL(lstm_fallback_kernel, dim3(2048), dim3(NTHREADS), 0, stream,
                           x, hprev, cprev, Wx, Wh, bh, out);
    }
}

// Round 3
// 173.776 us; speedup vs baseline: 2.0119x; 1.1023x over previous
//
#include <hip/hip_runtime.h>
#include <hip/hip_bf16.h>
#include <stdint.h>

#define B_DIM 8192
#define I_DIM 1024
#define H_DIM 1024
#define KTOT  2048
#define NTILES 32          // KTOT / 64

typedef __attribute__((ext_vector_type(8))) short short8;
typedef __attribute__((ext_vector_type(4))) float f32x4;

static __device__ __forceinline__ short f2b(float f) {
    __bf16 h = (__bf16)f;
    return __builtin_bit_cast(short, h);
}

static __device__ __forceinline__ short8 pack8(float4 a, float4 b) {
    short8 s;
    s[0] = f2b(a.x); s[1] = f2b(a.y); s[2] = f2b(a.z); s[3] = f2b(a.w);
    s[4] = f2b(b.x); s[5] = f2b(b.y); s[6] = f2b(b.z); s[7] = f2b(b.w);
    return s;
}

static __device__ __forceinline__ float sigmoid_f(float x) {
    return 1.0f / (1.0f + __expf(-x));
}

static __device__ __forceinline__ float tanh_fast(float x) {
    x = fminf(fmaxf(x, -15.0f), 15.0f);
    float e = __expf(2.0f * x);
    return (e - 1.0f) / (e + 1.0f);
}

static __device__ __forceinline__ void load_lds16(const void* gptr, void* lptr) {
    __builtin_amdgcn_global_load_lds(
        (const __attribute__((address_space(1))) uint32_t*)gptr,
        (__attribute__((address_space(3))) uint32_t*)lptr, 16, 0, 0);
}

// ---------------------------------------------------------------------------
// Pass 1: fp32 -> bf16 conversion into workspace (row-major).
//   A_ws [8192][2048]: k<1024 from x, k>=1024 from hprev
//   B_ws [4096][2048]: row n = gate*1024+h; k<1024 from Wx, k>=1024 from Wh
// ---------------------------------------------------------------------------
__global__ __launch_bounds__(256) void convert_kernel(
    const float* __restrict__ x, const float* __restrict__ h,
    const float* __restrict__ wx, const float* __restrict__ wh,
    short* __restrict__ Aw, short* __restrict__ Bw)
{
    const int64_t nx = (int64_t)B_DIM * I_DIM / 8;
    const int64_t nw = (int64_t)4 * H_DIM * I_DIM / 8;
    const int64_t total = 2 * nx + 2 * nw;
    for (int64_t g = (int64_t)blockIdx.x * blockDim.x + threadIdx.x; g < total;
         g += (int64_t)gridDim.x * blockDim.x) {
        const float* src;
        short* dst;
        if (g < nx) {
            int64_t r = g >> 7, kc = (g & 127) * 8;
            src = x + g * 8; dst = Aw + r * 2048 + kc;
        } else if (g < 2 * nx) {
            int64_t gg = g - nx;
            int64_t r = gg >> 7, kc = (gg & 127) * 8;
            src = h + gg * 8; dst = Aw + r * 2048 + 1024 + kc;
        } else if (g < 2 * nx + nw) {
            int64_t gg = g - 2 * nx;
            int64_t r = gg >> 7, kc = (gg & 127) * 8;
            src = wx + gg * 8; dst = Bw + r * 2048 + kc;
        } else {
            int64_t gg = g - 2 * nx - nw;
            int64_t r = gg >> 7, kc = (gg & 127) * 8;
            src = wh + gg * 8; dst = Bw + r * 2048 + 1024 + kc;
        }
        float4 v0 = ((const float4*)src)[0];
        float4 v1 = ((const float4*)src)[1];
        *(short8*)dst = pack8(v0, v1);
    }
}

// ---------------------------------------------------------------------------
// Pass 2: 256x256-tile 8-phase GEMM (BK=64 in two K-halves) with counted
// vmcnt, fragment-tile-ordered LDS (zero bank conflicts), fused LSTM epilogue.
// 512 threads = 8 waves (2 M x 4 N); per-wave output 128 x 64 (= 4 gates x 16 h).
// LDS 128 KiB: A[2 dbuf][2 khalf][16 fragtile][64 lane][16B], B likewise.
// ---------------------------------------------------------------------------

// short-index offsets into dynamic LDS
#define AOFF(d, kp, f) ((d) * 16384 + (kp) * 8192 + (f) * 512)
#define BOFF(d, kp, f) (32768 + (d) * 16384 + (kp) * 8192 + (f) * 512)

#define STAGE_A(dn, kh, tkp) \
    load_lds16(aSrc0 + (size_t)(tkp) * 64 + (kh) * 32, &smem[AOFF(dn, kh, 2 * w)]); \
    load_lds16(aSrc1 + (size_t)(tkp) * 64 + (kh) * 32, &smem[AOFF(dn, kh, 2 * w + 1)]);

#define STAGE_B(dn, kh, tkp) \
    load_lds16(bSrc0 + (size_t)(tkp) * 64 + (kh) * 32, &smem[BOFF(dn, kh, 2 * w)]); \
    load_lds16(bSrc1 + (size_t)(tkp) * 64 + (kh) * 32, &smem[BOFF(dn, kh, 2 * w + 1)]);

#define VM4 asm volatile("s_waitcnt vmcnt(4)" ::: "memory");

#define PHASE(d, kp, mh, STAGE_STMT, EXTRAWAIT) do { \
    short8 av[4], bv[4]; \
    _Pragma("unroll") \
    for (int i = 0; i < 4; ++i) \
        av[i] = *(const short8*)&smem[AOFF(d, kp, wm * 8 + (mh) * 4 + i) + lane * 8]; \
    _Pragma("unroll") \
    for (int j = 0; j < 4; ++j) \
        bv[j] = *(const short8*)&smem[BOFF(d, kp, wn * 4 + j) + lane * 8]; \
    STAGE_STMT \
    __builtin_amdgcn_s_barrier(); \
    asm volatile("s_waitcnt lgkmcnt(0)" ::: "memory"); \
    __builtin_amdgcn_sched_barrier(0); \
    __builtin_amdgcn_s_setprio(1); \
    _Pragma("unroll") \
    for (int i = 0; i < 4; ++i) \
        _Pragma("unroll") \
        for (int j = 0; j < 4; ++j) \
            acc[(mh) * 4 + i][j] = __builtin_amdgcn_mfma_f32_16x16x32_bf16( \
                av[i], bv[j], acc[(mh) * 4 + i][j], 0, 0, 0); \
    __builtin_amdgcn_s_setprio(0); \
    EXTRAWAIT \
    __builtin_amdgcn_s_barrier(); \
} while (0)

__global__ __launch_bounds__(512, 2) void lstm_gemm8_kernel(
    const short* __restrict__ Aw, const short* __restrict__ Bw,
    const float* __restrict__ cprev, const float* __restrict__ bh,
    float* __restrict__ out)
{
    extern __shared__ __align__(16) short smem[];

    // XCD-aware swizzle: 512 blocks, 8 XCDs, bijective
    int bid = blockIdx.x;
    bid = (bid & 7) * 64 + (bid >> 3);
    const int bm = bid >> 4;     // 0..31  M-tile (256 rows)
    const int bn = bid & 15;     // 0..15  h-tile (64 h)
    const int m0 = bm * 256;
    const int h0 = bn * 64;

    const int t    = threadIdx.x;
    const int lane = t & 63;
    const int w    = t >> 6;     // wave 0..7
    const int wm   = w >> 2;     // 0..1
    const int wn   = w & 3;      // 0..3
    const int lc   = lane & 15;
    const int lk   = lane >> 4;  // k-slot 0..3

    // staging sources: wave w stages fragment-tiles f = 2w, 2w+1 of each half.
    // A fragtile f: global (row m0 + f*16 + lc, k = tk*64 + kh*32 + lk*8)
    const short* aSrc0 = Aw + (size_t)(m0 + (2 * w + 0) * 16 + lc) * 2048 + lk * 8;
    const short* aSrc1 = Aw + (size_t)(m0 + (2 * w + 1) * 16 + lc) * 2048 + lk * 8;
    // B fragtile cf: col n = bn*256 + cf*16 + lc -> B_ws row (cf&3)*1024 + h0 + (cf>>2)*16 + lc
    const int cf0 = 2 * w, cf1 = 2 * w + 1;
    const short* bSrc0 = Bw + (size_t)((cf0 & 3) * 1024 + h0 + ((cf0 >> 2) << 4) + lc) * 2048 + lk * 8;
    const short* bSrc1 = Bw + (size_t)((cf1 & 3) * 1024 + h0 + ((cf1 >> 2) << 4) + lc) * 2048 + lk * 8;

    f32x4 acc[8][4] = {};   // [m-frag][gate]

    // prologue: stage tile 0 fully into dbuf 0; wait for its k0 halves
    STAGE_A(0, 0, 0)
    STAGE_B(0, 0, 0)
    STAGE_A(0, 1, 0)
    STAGE_B(0, 1, 0)
    asm volatile("s_waitcnt vmcnt(4)" ::: "memory");
    __builtin_amdgcn_s_barrier();

    #pragma unroll 1
    for (int tk2 = 0; tk2 < 16; ++tk2) {
        const int t1  = 2 * tk2 + 1;                   // tile for dbuf 1
        const int tp1 = (t1 + 1 < NTILES) ? t1 + 1 : t1; // prefetch for dbuf 0
        // tile 2*tk2 from dbuf 0, staging tile t1 into dbuf 1
        PHASE(0, 0, 0, STAGE_A(1, 0, t1), );
        PHASE(0, 0, 1, STAGE_B(1, 0, t1), VM4);
        PHASE(0, 1, 0, STAGE_A(1, 1, t1), );
        PHASE(0, 1, 1, STAGE_B(1, 1, t1), VM4);
        // tile t1 from dbuf 1, staging tile t1+1 into dbuf 0
        PHASE(1, 0, 0, STAGE_A(0, 0, tp1), );
        PHASE(1, 0, 1, STAGE_B(0, 0, tp1), VM4);
        PHASE(1, 1, 0, STAGE_A(0, 1, tp1), );
        PHASE(1, 1, 1, STAGE_B(0, 1, tp1), VM4);
    }
    asm volatile("s_waitcnt vmcnt(0)" ::: "memory");

    // ---- fused LSTM epilogue, in-register ----
    // D layout: col = lane&15 (h), row = (lane>>4)*4 + reg
    const int rg = lane >> 4;
    const int h  = h0 + wn * 16 + lc;
    const float b_i = bh[0 * H_DIM + h];
    const float b_f = bh[1 * H_DIM + h];
    const float b_g = bh[2 * H_DIM + h];
    const float b_o = bh[3 * H_DIM + h];

    #pragma unroll
    for (int mf = 0; mf < 8; ++mf) {
        #pragma unroll
        for (int r = 0; r < 4; ++r) {
            const int row = m0 + wm * 128 + mf * 16 + rg * 4 + r;
            const float pi = acc[mf][0][r] + b_i;
            const float pf = acc[mf][1][r] + b_f;
            const float pg = acc[mf][2][r] + b_g;
            const float po = acc[mf][3][r] + b_o;
            const float iv = sigmoid_f(pi);
            const float fv = sigmoid_f(pf);
            const float gv = tanh_fast(pg);
            const float ov = sigmoid_f(po);
            const float cp = cprev[(size_t)row * H_DIM + h];
            const float cn = fv * cp + iv * gv;
            const float hn = ov * tanh_fast(cn);
            out[(size_t)row * H_DIM + h] = hn;
            out[(size_t)B_DIM * H_DIM + (size_t)row * H_DIM + h] = cn;
        }
    }
}

// ---------------------------------------------------------------------------
// Fallback (round-1 style, no workspace) — kept for safety.
// ---------------------------------------------------------------------------
static __device__ __forceinline__ int swz(int row, int k) {
    int byte = (row << 7) + (k << 1);
    byte ^= (row & 7) << 4;
    return byte >> 1;
}

__global__ __launch_bounds__(256, 2) void lstm_fallback_kernel(
    const float* __restrict__ x, const float* __restrict__ hprev,
    const float* __restrict__ cprev, const float* __restrict__ Wx,
    const float* __restrict__ Wh, const float* __restrict__ bh,
    float* __restrict__ out)
{
    __shared__ __align__(16) short As[128 * 64];
    __shared__ __align__(16) short Bs[128 * 64];

    int bid = blockIdx.x;
    bid = (bid & 7) * 256 + (bid >> 3);
    const int mt = bid >> 5;
    const int ht = bid & 31;
    const int m0 = mt * 128;
    const int h0 = ht * 32;

    const int t    = threadIdx.x;
    const int lane = t & 63;
    const int w    = t >> 6;
    const int wr   = w >> 1;
    const int wc   = w & 1;

    const int srow = t >> 3;
    const int sk   = (t & 7) * 8;

    f32x4 acc[4][4] = {};

    #pragma unroll 1
    for (int phase = 0; phase < 2; ++phase) {
        const float* __restrict__ Ap = phase ? hprev : x;
        const float* __restrict__ Bp = phase ? Wh : Wx;
        #pragma unroll 1
        for (int kk = 0; kk < 1024; kk += 64) {
            __syncthreads();
            #pragma unroll
            for (int p = 0; p < 4; ++p) {
                const int row = srow + p * 32;
                const float4* src = (const float4*)(Ap + (size_t)(m0 + row) * I_DIM + kk + sk);
                *(short8*)&As[swz(row, sk)] = pack8(src[0], src[1]);
            }
            #pragma unroll
            for (int p = 0; p < 4; ++p) {
                const int n    = srow + p * 32;
                const int gate = (n >> 4) & 3;
                const int hcol = h0 + ((n >> 6) << 4) + (n & 15);
                const float4* src = (const float4*)(Bp + (size_t)((gate << 10) + hcol) * 1024 + kk + sk);
                *(short8*)&Bs[swz(n, sk)] = pack8(src[0], src[1]);
            }
            __syncthreads();
            #pragma unroll
            for (int ks = 0; ks < 2; ++ks) {
                const int kb = ks * 32 + ((lane >> 4) << 3);
                short8 a[4], b[4];
                #pragma unroll
                for (int m = 0; m < 4; ++m)
                    a[m] = *(const short8*)&As[swz(wr * 64 + m * 16 + (lane & 15), kb)];
                #pragma unroll
                for (int j = 0; j < 4; ++j)
                    b[j] = *(const short8*)&Bs[swz(wc * 64 + j * 16 + (lane & 15), kb)];
                #pragma unroll
                for (int m = 0; m < 4; ++m)
                    #pragma unroll
                    for (int j = 0; j < 4; ++j)
                        acc[m][j] = __builtin_amdgcn_mfma_f32_16x16x32_bf16(a[m], b[j], acc[m][j], 0, 0, 0);
            }
        }
    }

    const int cl = lane & 15;
    const int rg = lane >> 4;
    const int h  = h0 + wc * 16 + cl;
    const float b_i = bh[0 * H_DIM + h];
    const float b_f = bh[1 * H_DIM + h];
    const float b_g = bh[2 * H_DIM + h];
    const float b_o = bh[3 * H_DIM + h];

    #pragma unroll
    for (int m = 0; m < 4; ++m) {
        #pragma unroll
        for (int r = 0; r < 4; ++r) {
            const int row = m0 + wr * 64 + m * 16 + rg * 4 + r;
            const float pi = acc[m][0][r] + b_i;
            const float pf = acc[m][1][r] + b_f;
            const float pg = acc[m][2][r] + b_g;
            const float po = acc[m][3][r] + b_o;
            const float iv = sigmoid_f(pi);
            const float fv = sigmoid_f(pf);
            const float gv = tanh_fast(pg);
            const float ov = sigmoid_f(po);
            const float cp = cprev[(size_t)row * H_DIM + h];
            const float cn = fv * cp + iv * gv;
            const float hn = ov * tanh_fast(cn);
            out[(size_t)row * H_DIM + h] = hn;
            out[(size_t)B_DIM * H_DIM + (size_t)row * H_DIM + h] = cn;
        }
    }
}

extern "C" void kernel_launch(void* const* d_in, const int* in_sizes, int n_in,
                              void* d_out, int out_size, void* d_ws, size_t ws_size,
                              hipStream_t stream) {
    const float* x     = (const float*)d_in[0];
    const float* hprev = (const float*)d_in[1];
    const float* cprev = (const float*)d_in[2];
    const float* Wx    = (const float*)d_in[3];
    const float* Wh    = (const float*)d_in[4];
    const float* bh    = (const float*)d_in[5];
    float* out = (float*)d_out;

    const size_t need = ((size_t)B_DIM * 2048 + (size_t)4096 * 2048) * sizeof(short);
    if (ws_size >= need && d_ws != nullptr) {
        // allow 128 KiB dynamic LDS (no-op if already allowed); not a stream op
        (void)hipFuncSetAttribute((const void*)lstm_gemm8_kernel,
                                  hipFuncAttributeMaxDynamicSharedMemorySize, 131072);
        short* Aw = (short*)d_ws;
        short* Bw = Aw + (size_t)B_DIM * 2048;
        hipLaunchKernelGGL(convert_kernel, dim3(2048), dim3(256), 0, stream,
                           x, hprev, Wx, Wh, Aw, Bw);
        hipLaunchKernelGGL(lstm_gemm8_kernel, dim3(512), dim3(512), 131072, stream,
                           Aw, Bw, cprev, bh, out);
    } else {
        hipLaunchKernelGGL(lstm_fallback_kernel, dim3(2048), dim3(256), 0, stream,
                           x, hprev, cprev, Wx, Wh, bh, out);
    }
}